// Round 5
// baseline (357.774 us; speedup 1.0000x reference)
//
#include <hip/hip_runtime.h>

#define B_   64
#define E_   1024
#define N_   512
#define D_   64
#define HID_ 128
#define T_   5

typedef __bf16 bf16x8 __attribute__((ext_vector_type(8)));
typedef float f32x4 __attribute__((ext_vector_type(4)));

__device__ __forceinline__ unsigned short f2bu(float f) {
    union { float f; unsigned int u; } v; v.f = f;
    unsigned int r = (v.u + 0x7fffu + ((v.u >> 16) & 1u)) >> 16;  // RNE
    return (unsigned short)r;
}

#define MFMA16(a, b, c) __builtin_amdgcn_mfma_f32_16x16x32_bf16((a), (b), (c), 0, 0, 0)

// ---------------------------------------------------------------------------
// Prep: W1[t][d][h] -> W1T[t][h][d] bf16 ; W2[t][h][d] -> W2T[t][d][h] bf16
// ---------------------------------------------------------------------------
__global__ __launch_bounds__(256) void k_prep_w(const float* __restrict__ W1,
                                                const float* __restrict__ W2,
                                                unsigned short* __restrict__ W1T,
                                                unsigned short* __restrict__ W2T) {
    int idx = blockIdx.x * 256 + threadIdx.x;
    if (idx < T_ * HID_ * D_) {
        int t = idx / (HID_ * D_), rem = idx % (HID_ * D_);
        int h = rem / D_, d = rem % D_;
        W1T[idx] = f2bu(W1[(t * D_ + d) * HID_ + h]);
    } else {
        int j = idx - T_ * HID_ * D_;
        int t = j / (D_ * HID_), rem = j % (D_ * HID_);
        int d = rem / HID_, h = rem % HID_;
        W2T[j] = f2bu(W2[(t * HID_ + h) * D_ + d]);
    }
}

// ---------------------------------------------------------------------------
// Prep: ori[b][n][d] -> oriT[b][d][n] bf16, and out[b][n][64+d] = ori (fp32)
// grid (8, 64): x = n-tile of 64, y = b
// ---------------------------------------------------------------------------
__global__ __launch_bounds__(256) void k_ori_prep(const float* __restrict__ ori,
                                                  float* __restrict__ out,
                                                  unsigned short* __restrict__ oriT) {
    int b = blockIdx.y, n0 = blockIdx.x * 64;
    __shared__ float tl[64 * 65];
    int tid = threadIdx.x;
    int dl = tid & 63;
    #pragma unroll 4
    for (int p = 0; p < 16; ++p) {
        int nn = p * 4 + (tid >> 6);
        float v = ori[(size_t)(b * N_ + n0 + nn) * D_ + dl];
        out[(size_t)(b * N_ + n0 + nn) * 128 + 64 + dl] = v;
        tl[dl * 65 + nn] = v;
    }
    __syncthreads();
    #pragma unroll 4
    for (int p = 0; p < 16; ++p) {
        int dd = p * 4 + (tid >> 6);
        oriT[(size_t)(b * D_ + dd) * N_ + n0 + dl] = f2bu(tl[dd * 65 + dl]);
    }
}

// ---------------------------------------------------------------------------
// Prep: H fp32 -> Hbf[b][e][n] bf16  AND  HbfT[b][n][e] bf16 (LDS transpose).
// One fp32 read of H total for the whole pipeline.
// grid (16, 8, 64): x = e-tile of 64, y = n-tile of 64, z = b. 256 threads.
// thread: e-row r = tid>>2, n-group cg = tid&3 (16 floats).
// ---------------------------------------------------------------------------
__global__ __launch_bounds__(256) void k_prep_H(const float* __restrict__ H,
                                                unsigned short* __restrict__ Hbf,
                                                unsigned short* __restrict__ HbfT) {
    int e0 = blockIdx.x * 64, n0 = blockIdx.y * 64, b = blockIdx.z;
    __shared__ __align__(16) unsigned short tl[64 * 72];
    int tid = threadIdx.x, r = tid >> 2, cg = tid & 3;
    const float* src = &H[((size_t)b * E_ + e0 + r) * N_ + n0 + cg * 16];
    unsigned short v[16];
    #pragma unroll
    for (int m = 0; m < 4; ++m) {
        float4 f = *(const float4*)&src[m * 4];
        v[m * 4 + 0] = f2bu(f.x); v[m * 4 + 1] = f2bu(f.y);
        v[m * 4 + 2] = f2bu(f.z); v[m * 4 + 3] = f2bu(f.w);
    }
    unsigned short* dst = &Hbf[((size_t)b * E_ + e0 + r) * N_ + n0 + cg * 16];
    *(uint4*)&dst[0] = *(const uint4*)&v[0];
    *(uint4*)&dst[8] = *(const uint4*)&v[8];
    #pragma unroll
    for (int m = 0; m < 16; ++m) tl[(cg * 16 + m) * 72 + r] = v[m];
    __syncthreads();
    unsigned short* dstT = &HbfT[((size_t)b * N_ + n0 + r) * E_ + e0 + cg * 16];
    *(uint4*)&dstT[0] = *(const uint4*)&tl[r * 72 + cg * 16];
    *(uint4*)&dstT[8] = *(const uint4*)&tl[r * 72 + cg * 16 + 8];
}

// ---------------------------------------------------------------------------
// K1: edges[b][e][d] = sum_n Hbf[b][e][n] * ori[b][n][d]   (bf16 out)
// grid (8, 64): x = e-tile of 128, y = b. 256 threads = 4 waves. BK=64.
// Pure uint4 staging (no fp32 conversion in-loop).
// ---------------------------------------------------------------------------
__global__ __launch_bounds__(256) void k_gemm_edges(const unsigned short* __restrict__ Hbf,
                                                    const unsigned short* __restrict__ oriT,
                                                    unsigned short* __restrict__ edges) {
    int b = blockIdx.y, e0 = blockIdx.x * 128;
    __shared__ __align__(16) unsigned short aA[128 * 72];
    __shared__ __align__(16) unsigned short bB[64 * 72];
    int tid = threadIdx.x, w = tid >> 6, l = tid & 63, q = l >> 4, c = l & 15;
    const f32x4 zero = {0.f, 0.f, 0.f, 0.f};
    f32x4 acc[2][4];
    #pragma unroll
    for (int fm = 0; fm < 2; ++fm)
        #pragma unroll
        for (int fn = 0; fn < 4; ++fn) acc[fm][fn] = zero;

    for (int ks = 0; ks < 8; ++ks) {
        int k0 = ks * 64;
        #pragma unroll
        for (int p = 0; p < 4; ++p) {
            int u = p * 256 + tid, r = u >> 3, sg = u & 7;
            *(uint4*)&aA[r * 72 + sg * 8] =
                *(const uint4*)&Hbf[((size_t)b * E_ + e0 + r) * N_ + k0 + sg * 8];
        }
        #pragma unroll
        for (int p = 0; p < 2; ++p) {
            int u = p * 256 + tid, r = u >> 3, sg = u & 7;
            *(uint4*)&bB[r * 72 + sg * 8] =
                *(const uint4*)&oriT[((size_t)b * D_ + r) * N_ + k0 + sg * 8];
        }
        __syncthreads();
        #pragma unroll
        for (int h = 0; h < 2; ++h) {
            bf16x8 a0 = *(const bf16x8*)&aA[(w * 32 + c) * 72 + h * 32 + q * 8];
            bf16x8 a1 = *(const bf16x8*)&aA[(w * 32 + 16 + c) * 72 + h * 32 + q * 8];
            #pragma unroll
            for (int fn = 0; fn < 4; ++fn) {
                bf16x8 bb = *(const bf16x8*)&bB[(fn * 16 + c) * 72 + h * 32 + q * 8];
                acc[0][fn] = MFMA16(a0, bb, acc[0][fn]);
                acc[1][fn] = MFMA16(a1, bb, acc[1][fn]);
            }
        }
        __syncthreads();
    }
    #pragma unroll
    for (int fm = 0; fm < 2; ++fm)
        #pragma unroll
        for (int fn = 0; fn < 4; ++fn)
            #pragma unroll
            for (int i = 0; i < 4; ++i) {
                int e = e0 + w * 32 + fm * 16 + q * 4 + i;
                int d = fn * 16 + c;
                edges[((size_t)b * E_ + e) * D_ + d] = f2bu(acc[fm][fn][i]);
            }
}

// ---------------------------------------------------------------------------
// K2: fused per-type MLP + mixture (MFMA). Unchanged from passing round 4.
// ---------------------------------------------------------------------------
__global__ __launch_bounds__(256) void k_mlp(const unsigned short* __restrict__ edges,
                                             const float* __restrict__ ed,
                                             const float* __restrict__ b1,
                                             const float* __restrict__ b2,
                                             const unsigned short* __restrict__ W1T,
                                             const unsigned short* __restrict__ W2T,
                                             unsigned short* __restrict__ efT) {
    int bx = blockIdx.x;
    int b = bx >> 4, e0 = (bx & 15) * 64;
    __shared__ __align__(16) unsigned short a_sh[64 * 72];
    __shared__ __align__(16) unsigned short w_sh[128 * 72];
    __shared__ __align__(16) unsigned short h_sh[64 * 136];
    __shared__ float wd_sh[320];
    __shared__ float b1_sh[640];
    __shared__ float b2_sh[320];
    int tid = threadIdx.x, w = tid >> 6, l = tid & 63, q = l >> 4, c = l & 15;

    #pragma unroll
    for (int p = 0; p < 2; ++p) {
        int u = p * 256 + tid, r = u >> 3, sg = u & 7;
        *(uint4*)&a_sh[r * 72 + sg * 8] =
            *(const uint4*)&edges[((size_t)b * E_ + e0 + r) * D_ + sg * 8];
    }
    for (int u = tid; u < 320; u += 256) wd_sh[u] = ed[((size_t)b * E_ + e0) * T_ + u];
    for (int u = tid; u < 640; u += 256) b1_sh[u] = b1[u];
    for (int u = tid; u < 320; u += 256) b2_sh[u] = b2[u];

    const f32x4 zero = {0.f, 0.f, 0.f, 0.f};
    f32x4 y[4];
    #pragma unroll
    for (int fn = 0; fn < 4; ++fn) y[fn] = zero;

    for (int t = 0; t < T_; ++t) {
        __syncthreads();
        #pragma unroll
        for (int p = 0; p < 4; ++p) {
            int u = p * 256 + tid, hh = u >> 3, sg = u & 7;
            *(uint4*)&w_sh[hh * 72 + sg * 8] =
                *(const uint4*)&W1T[(t * HID_ + hh) * D_ + sg * 8];
        }
        __syncthreads();
        f32x4 hc[8];
        #pragma unroll
        for (int fn = 0; fn < 8; ++fn) hc[fn] = zero;
        #pragma unroll
        for (int ks = 0; ks < 2; ++ks) {
            bf16x8 a = *(const bf16x8*)&a_sh[(w * 16 + c) * 72 + ks * 32 + q * 8];
            #pragma unroll
            for (int fn = 0; fn < 8; ++fn) {
                bf16x8 bb = *(const bf16x8*)&w_sh[(fn * 16 + c) * 72 + ks * 32 + q * 8];
                hc[fn] = MFMA16(a, bb, hc[fn]);
            }
        }
        float wv[4];
        #pragma unroll
        for (int i = 0; i < 4; ++i) wv[i] = wd_sh[(w * 16 + q * 4 + i) * T_ + t];
        #pragma unroll
        for (int fn = 0; fn < 8; ++fn) {
            float b1v = b1_sh[t * HID_ + fn * 16 + c];
            #pragma unroll
            for (int i = 0; i < 4; ++i) {
                float v = hc[fn][i] + b1v;
                v = fmaxf(v, 0.0f) * wv[i];
                h_sh[(w * 16 + q * 4 + i) * 136 + fn * 16 + c] = f2bu(v);
            }
        }
        __syncthreads();
        #pragma unroll
        for (int p = 0; p < 4; ++p) {
            int u = p * 256 + tid, dd = u >> 4, sg = u & 15;
            *(uint4*)&w_sh[dd * 136 + sg * 8] =
                *(const uint4*)&W2T[(t * D_ + dd) * HID_ + sg * 8];
        }
        __syncthreads();
        #pragma unroll
        for (int ks = 0; ks < 4; ++ks) {
            bf16x8 a = *(const bf16x8*)&h_sh[(w * 16 + c) * 136 + ks * 32 + q * 8];
            #pragma unroll
            for (int fn = 0; fn < 4; ++fn) {
                bf16x8 bb = *(const bf16x8*)&w_sh[(fn * 16 + c) * 136 + ks * 32 + q * 8];
                y[fn] = MFMA16(a, bb, y[fn]);
            }
        }
    }
    #pragma unroll
    for (int fn = 0; fn < 4; ++fn) {
        int d = fn * 16 + c;
        ushort4 o;
        #pragma unroll
        for (int i = 0; i < 4; ++i) {
            int r = w * 16 + q * 4 + i;
            float s = y[fn][i];
            #pragma unroll
            for (int t = 0; t < T_; ++t) s += wd_sh[r * T_ + t] * b2_sh[t * D_ + d];
            ((unsigned short*)&o)[i] = f2bu(s);
        }
        *(ushort4*)&efT[((size_t)b * D_ + d) * E_ + e0 + w * 16 + q * 4] = o;
    }
}

// ---------------------------------------------------------------------------
// K3: out[b][n][d] = sum_e H[b][e][n] * ef[b][e][d]  — computed as outT tile:
// M = d (64, all), N = n-tile of 64, K = e (1024), BK=64.
// A = efT[b][d][e] rows (e-contig), B = HbfT[b][n][e] rows (e-contig):
// NO transpose staging. grid (8, 64) = 512 blocks. Coalesced float4 stores.
// ---------------------------------------------------------------------------
__global__ __launch_bounds__(256) void k_gemm_out(const unsigned short* __restrict__ HbfT,
                                                  const unsigned short* __restrict__ efT,
                                                  float* __restrict__ out) {
    int b = blockIdx.y, n0 = blockIdx.x * 64;
    __shared__ __align__(16) unsigned short aA[64 * 72];   // efT  [d][e]
    __shared__ __align__(16) unsigned short bB[64 * 72];   // HbfT [n][e]
    int tid = threadIdx.x, w = tid >> 6, l = tid & 63, q = l >> 4, c = l & 15;
    const f32x4 zero = {0.f, 0.f, 0.f, 0.f};
    f32x4 acc[4];
    #pragma unroll
    for (int fm = 0; fm < 4; ++fm) acc[fm] = zero;

    for (int ks = 0; ks < 16; ++ks) {
        int k0 = ks * 64;
        #pragma unroll
        for (int p = 0; p < 2; ++p) {
            int u = p * 256 + tid, r = u >> 3, sg = u & 7;
            *(uint4*)&aA[r * 72 + sg * 8] =
                *(const uint4*)&efT[((size_t)b * D_ + r) * E_ + k0 + sg * 8];
        }
        #pragma unroll
        for (int p = 0; p < 2; ++p) {
            int u = p * 256 + tid, r = u >> 3, sg = u & 7;
            *(uint4*)&bB[r * 72 + sg * 8] =
                *(const uint4*)&HbfT[((size_t)b * N_ + n0 + r) * E_ + k0 + sg * 8];
        }
        __syncthreads();
        #pragma unroll
        for (int h = 0; h < 2; ++h) {
            bf16x8 bfr = *(const bf16x8*)&bB[(w * 16 + c) * 72 + h * 32 + q * 8];
            #pragma unroll
            for (int fm = 0; fm < 4; ++fm) {
                bf16x8 afr = *(const bf16x8*)&aA[(fm * 16 + c) * 72 + h * 32 + q * 8];
                acc[fm] = MFMA16(afr, bfr, acc[fm]);
            }
        }
        __syncthreads();
    }
    // D[m=d][n]: row = q*4+i (d), col = c (n). Lane -> out[b][n0+w*16+c][fm*16+q*4 ..+3]
    #pragma unroll
    for (int fm = 0; fm < 4; ++fm) {
        *(f32x4*)&out[((size_t)b * N_ + n0 + w * 16 + c) * 128 + fm * 16 + q * 4] = acc[fm];
    }
}

// ---------------------------------------------------------------------------
extern "C" void kernel_launch(void* const* d_in, const int* in_sizes, int n_in,
                              void* d_out, int out_size, void* d_ws, size_t ws_size,
                              hipStream_t stream) {
    const float* ed  = (const float*)d_in[0];  // [B,E,T]
    const float* H   = (const float*)d_in[1];  // [B,E,N]
    const float* ori = (const float*)d_in[2];  // [B,N,64]
    const float* W1  = (const float*)d_in[3];  // [T,64,128]
    const float* b1  = (const float*)d_in[4];  // [T,128]
    const float* W2  = (const float*)d_in[5];  // [T,128,64]
    const float* b2  = (const float*)d_in[6];  // [T,64]
    float* out = (float*)d_out;

    char* ws = (char*)d_ws;
    unsigned short* oriT  = (unsigned short*)ws; ws += (size_t)B_ * D_ * N_ * 2;    // 4 MB
    unsigned short* W1T   = (unsigned short*)ws; ws += (size_t)T_ * HID_ * D_ * 2;
    unsigned short* W2T   = (unsigned short*)ws; ws += (size_t)T_ * D_ * HID_ * 2;
    unsigned short* edges = (unsigned short*)ws; ws += (size_t)B_ * E_ * D_ * 2;    // 8 MB
    unsigned short* efT   = (unsigned short*)ws; ws += (size_t)B_ * D_ * E_ * 2;    // 8 MB
    unsigned short* Hbf   = (unsigned short*)ws; ws += (size_t)B_ * E_ * N_ * 2;    // 67 MB
    unsigned short* HbfT  = (unsigned short*)ws; ws += (size_t)B_ * N_ * E_ * 2;    // 67 MB

    hipLaunchKernelGGL(k_prep_w, dim3(320), dim3(256), 0, stream, W1, W2, W1T, W2T);
    hipLaunchKernelGGL(k_ori_prep, dim3(8, 64), dim3(256), 0, stream, ori, out, oriT);
    hipLaunchKernelGGL(k_prep_H, dim3(16, 8, 64), dim3(256), 0, stream, H, Hbf, HbfT);
    hipLaunchKernelGGL(k_gemm_edges, dim3(8, 64), dim3(256), 0, stream, Hbf, oriT, edges);
    hipLaunchKernelGGL(k_mlp, dim3(1024), dim3(256), 0, stream, edges, ed, b1, b2, W1T, W2T, efT);
    hipLaunchKernelGGL(k_gemm_out, dim3(8, 64), dim3(256), 0, stream, HbfT, efT, out);
}

// Round 7
// 296.141 us; speedup vs baseline: 1.2081x; 1.2081x over previous
//
#include <hip/hip_runtime.h>

#define B_   64
#define E_   1024
#define N_   512
#define D_   64
#define HID_ 128
#define T_   5

typedef __bf16 bf16x8 __attribute__((ext_vector_type(8)));
typedef float f32x4 __attribute__((ext_vector_type(4)));

__device__ __forceinline__ unsigned short f2bu(float f) {
    union { float f; unsigned int u; } v; v.f = f;
    unsigned int r = (v.u + 0x7fffu + ((v.u >> 16) & 1u)) >> 16;  // RNE
    return (unsigned short)r;
}

__device__ __forceinline__ unsigned int pack2(float lo, float hi) {
    union { __bf16 b[2]; unsigned int u; } v;
    v.b[0] = (__bf16)lo; v.b[1] = (__bf16)hi;   // RNE
    return v.u;
}

__device__ __forceinline__ uint4 cvt8(float4 a, float4 b) {
    union { __bf16 h[8]; uint4 u; } v;
    v.h[0] = (__bf16)a.x; v.h[1] = (__bf16)a.y; v.h[2] = (__bf16)a.z; v.h[3] = (__bf16)a.w;
    v.h[4] = (__bf16)b.x; v.h[5] = (__bf16)b.y; v.h[6] = (__bf16)b.z; v.h[7] = (__bf16)b.w;
    return v.u;
}

#define MFMA16(a, b, c) __builtin_amdgcn_mfma_f32_16x16x32_bf16((a), (b), (c), 0, 0, 0)

// ---------------------------------------------------------------------------
// Prep: W1[t][d][h] -> W1T[t][h][d] bf16 ; W2[t][h][d] -> W2T[t][d][h] bf16
// ---------------------------------------------------------------------------
__global__ __launch_bounds__(256) void k_prep_w(const float* __restrict__ W1,
                                                const float* __restrict__ W2,
                                                unsigned short* __restrict__ W1T,
                                                unsigned short* __restrict__ W2T) {
    int idx = blockIdx.x * 256 + threadIdx.x;
    if (idx < T_ * HID_ * D_) {
        int t = idx / (HID_ * D_), rem = idx % (HID_ * D_);
        int h = rem / D_, d = rem % D_;
        W1T[idx] = f2bu(W1[(t * D_ + d) * HID_ + h]);
    } else {
        int j = idx - T_ * HID_ * D_;
        int t = j / (D_ * HID_), rem = j % (D_ * HID_);
        int d = rem / HID_, h = rem % HID_;
        W2T[j] = f2bu(W2[(t * HID_ + h) * D_ + d]);
    }
}

// ---------------------------------------------------------------------------
// Prep: ori[b][n][d] -> oriT[b][d][n] bf16, and out[b][n][64+d] = ori (fp32)
// grid (8, 64): x = n-tile of 64, y = b
// ---------------------------------------------------------------------------
__global__ __launch_bounds__(256) void k_ori_prep(const float* __restrict__ ori,
                                                  float* __restrict__ out,
                                                  unsigned short* __restrict__ oriT) {
    int b = blockIdx.y, n0 = blockIdx.x * 64;
    __shared__ float tl[64 * 65];
    int tid = threadIdx.x;
    int dl = tid & 63;
    #pragma unroll 4
    for (int p = 0; p < 16; ++p) {
        int nn = p * 4 + (tid >> 6);
        float v = ori[(size_t)(b * N_ + n0 + nn) * D_ + dl];
        out[(size_t)(b * N_ + n0 + nn) * 128 + 64 + dl] = v;
        tl[dl * 65 + nn] = v;
    }
    __syncthreads();
    #pragma unroll 4
    for (int p = 0; p < 16; ++p) {
        int dd = p * 4 + (tid >> 6);
        oriT[(size_t)(b * D_ + dd) * N_ + n0 + dl] = f2bu(tl[dd * 65 + dl]);
    }
}

// ---------------------------------------------------------------------------
// K1: edges[b][e][d] = sum_n H[b][e][n] * ori[b][n][d]   (bf16 out)
// Reads fp32 H directly; converts inline with packed bf16 casts during
// A-staging. grid (8, 64): e-tile 128, b. 256 threads. BK=64.
// ---------------------------------------------------------------------------
__global__ __launch_bounds__(256) void k_gemm_edges(const float* __restrict__ H,
                                                    const unsigned short* __restrict__ oriT,
                                                    unsigned short* __restrict__ edges) {
    int b = blockIdx.y, e0 = blockIdx.x * 128;
    __shared__ __align__(16) unsigned short aA[128 * 72];
    __shared__ __align__(16) unsigned short bB[64 * 72];
    int tid = threadIdx.x, w = tid >> 6, l = tid & 63, q = l >> 4, c = l & 15;
    const f32x4 zero = {0.f, 0.f, 0.f, 0.f};
    f32x4 acc[2][4];
    #pragma unroll
    for (int fm = 0; fm < 2; ++fm)
        #pragma unroll
        for (int fn = 0; fn < 4; ++fn) acc[fm][fn] = zero;

    for (int ks = 0; ks < 8; ++ks) {
        int k0 = ks * 64;
        // stage A: 128 e-rows x 64 floats of H -> bf16 (packed cvt)
        #pragma unroll
        for (int p = 0; p < 4; ++p) {
            int u = p * 256 + tid, r = u >> 3, sg = u & 7;
            const float* s = &H[((size_t)b * E_ + e0 + r) * N_ + k0 + sg * 8];
            float4 f0 = *(const float4*)&s[0];
            float4 f1 = *(const float4*)&s[4];
            *(uint4*)&aA[r * 72 + sg * 8] = cvt8(f0, f1);
        }
        // stage B: oriT (bf16, n-contig) straight copy
        #pragma unroll
        for (int p = 0; p < 2; ++p) {
            int u = p * 256 + tid, r = u >> 3, sg = u & 7;
            *(uint4*)&bB[r * 72 + sg * 8] =
                *(const uint4*)&oriT[((size_t)b * D_ + r) * N_ + k0 + sg * 8];
        }
        __syncthreads();
        #pragma unroll
        for (int h = 0; h < 2; ++h) {
            bf16x8 a0 = *(const bf16x8*)&aA[(w * 32 + c) * 72 + h * 32 + q * 8];
            bf16x8 a1 = *(const bf16x8*)&aA[(w * 32 + 16 + c) * 72 + h * 32 + q * 8];
            #pragma unroll
            for (int fn = 0; fn < 4; ++fn) {
                bf16x8 bb = *(const bf16x8*)&bB[(fn * 16 + c) * 72 + h * 32 + q * 8];
                acc[0][fn] = MFMA16(a0, bb, acc[0][fn]);
                acc[1][fn] = MFMA16(a1, bb, acc[1][fn]);
            }
        }
        __syncthreads();
    }
    #pragma unroll
    for (int fm = 0; fm < 2; ++fm)
        #pragma unroll
        for (int fn = 0; fn < 4; ++fn)
            #pragma unroll
            for (int i = 0; i < 4; ++i) {
                int e = e0 + w * 32 + fm * 16 + q * 4 + i;
                int d = fn * 16 + c;
                edges[((size_t)b * E_ + e) * D_ + d] = f2bu(acc[fm][fn][i]);
            }
}

// ---------------------------------------------------------------------------
// K2: fused per-type MLP + mixture (MFMA). Unchanged (verified R4/R5).
// ---------------------------------------------------------------------------
__global__ __launch_bounds__(256) void k_mlp(const unsigned short* __restrict__ edges,
                                             const float* __restrict__ ed,
                                             const float* __restrict__ b1,
                                             const float* __restrict__ b2,
                                             const unsigned short* __restrict__ W1T,
                                             const unsigned short* __restrict__ W2T,
                                             unsigned short* __restrict__ efT) {
    int bx = blockIdx.x;
    int b = bx >> 4, e0 = (bx & 15) * 64;
    __shared__ __align__(16) unsigned short a_sh[64 * 72];
    __shared__ __align__(16) unsigned short w_sh[128 * 72];
    __shared__ __align__(16) unsigned short h_sh[64 * 136];
    __shared__ float wd_sh[320];
    __shared__ float b1_sh[640];
    __shared__ float b2_sh[320];
    int tid = threadIdx.x, w = tid >> 6, l = tid & 63, q = l >> 4, c = l & 15;

    #pragma unroll
    for (int p = 0; p < 2; ++p) {
        int u = p * 256 + tid, r = u >> 3, sg = u & 7;
        *(uint4*)&a_sh[r * 72 + sg * 8] =
            *(const uint4*)&edges[((size_t)b * E_ + e0 + r) * D_ + sg * 8];
    }
    for (int u = tid; u < 320; u += 256) wd_sh[u] = ed[((size_t)b * E_ + e0) * T_ + u];
    for (int u = tid; u < 640; u += 256) b1_sh[u] = b1[u];
    for (int u = tid; u < 320; u += 256) b2_sh[u] = b2[u];

    const f32x4 zero = {0.f, 0.f, 0.f, 0.f};
    f32x4 y[4];
    #pragma unroll
    for (int fn = 0; fn < 4; ++fn) y[fn] = zero;

    for (int t = 0; t < T_; ++t) {
        __syncthreads();
        #pragma unroll
        for (int p = 0; p < 4; ++p) {
            int u = p * 256 + tid, hh = u >> 3, sg = u & 7;
            *(uint4*)&w_sh[hh * 72 + sg * 8] =
                *(const uint4*)&W1T[(t * HID_ + hh) * D_ + sg * 8];
        }
        __syncthreads();
        f32x4 hc[8];
        #pragma unroll
        for (int fn = 0; fn < 8; ++fn) hc[fn] = zero;
        #pragma unroll
        for (int ks = 0; ks < 2; ++ks) {
            bf16x8 a = *(const bf16x8*)&a_sh[(w * 16 + c) * 72 + ks * 32 + q * 8];
            #pragma unroll
            for (int fn = 0; fn < 8; ++fn) {
                bf16x8 bb = *(const bf16x8*)&w_sh[(fn * 16 + c) * 72 + ks * 32 + q * 8];
                hc[fn] = MFMA16(a, bb, hc[fn]);
            }
        }
        float wv[4];
        #pragma unroll
        for (int i = 0; i < 4; ++i) wv[i] = wd_sh[(w * 16 + q * 4 + i) * T_ + t];
        #pragma unroll
        for (int fn = 0; fn < 8; ++fn) {
            float b1v = b1_sh[t * HID_ + fn * 16 + c];
            #pragma unroll
            for (int i = 0; i < 4; ++i) {
                float v = hc[fn][i] + b1v;
                v = fmaxf(v, 0.0f) * wv[i];
                h_sh[(w * 16 + q * 4 + i) * 136 + fn * 16 + c] = f2bu(v);
            }
        }
        __syncthreads();
        #pragma unroll
        for (int p = 0; p < 4; ++p) {
            int u = p * 256 + tid, dd = u >> 4, sg = u & 15;
            *(uint4*)&w_sh[dd * 136 + sg * 8] =
                *(const uint4*)&W2T[(t * D_ + dd) * HID_ + sg * 8];
        }
        __syncthreads();
        #pragma unroll
        for (int ks = 0; ks < 4; ++ks) {
            bf16x8 a = *(const bf16x8*)&h_sh[(w * 16 + c) * 136 + ks * 32 + q * 8];
            #pragma unroll
            for (int fn = 0; fn < 4; ++fn) {
                bf16x8 bb = *(const bf16x8*)&w_sh[(fn * 16 + c) * 136 + ks * 32 + q * 8];
                y[fn] = MFMA16(a, bb, y[fn]);
            }
        }
    }
    #pragma unroll
    for (int fn = 0; fn < 4; ++fn) {
        int d = fn * 16 + c;
        ushort4 o;
        #pragma unroll
        for (int i = 0; i < 4; ++i) {
            int r = w * 16 + q * 4 + i;
            float s = y[fn][i];
            #pragma unroll
            for (int t = 0; t < T_; ++t) s += wd_sh[r * T_ + t] * b2_sh[t * D_ + d];
            ((unsigned short*)&o)[i] = f2bu(s);
        }
        *(ushort4*)&efT[((size_t)b * D_ + d) * E_ + e0 + w * 16 + q * 4] = o;
    }
}

// ---------------------------------------------------------------------------
// K3: out[b][n][d] = sum_e H[b][e][n] * ef[b][e][d], computed as outT tile
// (M = d 64, N = n-tile 64, K = e 1024, BK = 64). A = efT rows (e-contig).
// B = H^T built inline: fp32 H rows pair-packed (bf16 x2 per uint) into
// bB32[n][e/2] stride 33 uints -> write bank (8cg+j+r2)%32 = 2-way (free).
// Fragments read as 4x ds_read_b32 (4 B align OK). grid (8, 64).
// ---------------------------------------------------------------------------
__global__ __launch_bounds__(256) void k_gemm_out(const float* __restrict__ H,
                                                  const unsigned short* __restrict__ efT,
                                                  float* __restrict__ out) {
    int b = blockIdx.y, n0 = blockIdx.x * 64;
    __shared__ __align__(16) unsigned short aA[64 * 72];   // efT [d][e]
    __shared__ unsigned int bB32[64 * 33];                 // H^T [n][e/2] pair-packed
    int tid = threadIdx.x, w = tid >> 6, l = tid & 63, q = l >> 4, c = l & 15;
    int r2 = tid >> 3, cg = tid & 7;                       // staging coords
    const f32x4 zero = {0.f, 0.f, 0.f, 0.f};
    f32x4 acc[4];
    #pragma unroll
    for (int fm = 0; fm < 4; ++fm) acc[fm] = zero;

    for (int ks = 0; ks < 16; ++ks) {
        int k0 = ks * 64;
        // stage A: efT rows (bf16, e-contig)
        #pragma unroll
        for (int p = 0; p < 2; ++p) {
            int u = p * 256 + tid, r = u >> 3, sg = u & 7;
            *(uint4*)&aA[r * 72 + sg * 8] =
                *(const uint4*)&efT[((size_t)b * D_ + r) * E_ + k0 + sg * 8];
        }
        // stage B: pair-pack transpose of H[k0..k0+64][n0..n0+64] fp32
        {
            const float* s0 = &H[((size_t)b * E_ + k0 + 2 * r2) * N_ + n0 + cg * 8];
            const float* s1 = s0 + N_;
            float4 f0 = *(const float4*)&s0[0], f1 = *(const float4*)&s0[4];
            float4 g0 = *(const float4*)&s1[0], g1 = *(const float4*)&s1[4];
            float r0[8] = {f0.x, f0.y, f0.z, f0.w, f1.x, f1.y, f1.z, f1.w};
            float r1[8] = {g0.x, g0.y, g0.z, g0.w, g1.x, g1.y, g1.z, g1.w};
            #pragma unroll
            for (int j = 0; j < 8; ++j)
                bB32[(cg * 8 + j) * 33 + r2] = pack2(r0[j], r1[j]);
        }
        __syncthreads();
        #pragma unroll
        for (int h = 0; h < 2; ++h) {
            union { unsigned int u[4]; bf16x8 v; } bb;
            #pragma unroll
            for (int i = 0; i < 4; ++i)
                bb.u[i] = bB32[(w * 16 + c) * 33 + h * 16 + q * 4 + i];
            #pragma unroll
            for (int fm = 0; fm < 4; ++fm) {
                bf16x8 afr = *(const bf16x8*)&aA[(fm * 16 + c) * 72 + h * 32 + q * 8];
                acc[fm] = MFMA16(afr, bb.v, acc[fm]);
            }
        }
        __syncthreads();
    }
    // D[m=d][col=n]: d = fm*16 + q*4 + i, n = n0 + w*16 + c  (same as R5)
    #pragma unroll
    for (int fm = 0; fm < 4; ++fm) {
        *(f32x4*)&out[((size_t)b * N_ + n0 + w * 16 + c) * 128 + fm * 16 + q * 4] = acc[fm];
    }
}

// ---------------------------------------------------------------------------
extern "C" void kernel_launch(void* const* d_in, const int* in_sizes, int n_in,
                              void* d_out, int out_size, void* d_ws, size_t ws_size,
                              hipStream_t stream) {
    const float* ed  = (const float*)d_in[0];  // [B,E,T]
    const float* H   = (const float*)d_in[1];  // [B,E,N]
    const float* ori = (const float*)d_in[2];  // [B,N,64]
    const float* W1  = (const float*)d_in[3];  // [T,64,128]
    const float* b1  = (const float*)d_in[4];  // [T,128]
    const float* W2  = (const float*)d_in[5];  // [T,128,64]
    const float* b2  = (const float*)d_in[6];  // [T,64]
    float* out = (float*)d_out;

    char* ws = (char*)d_ws;
    unsigned short* oriT  = (unsigned short*)ws; ws += (size_t)B_ * D_ * N_ * 2;    // 4 MB
    unsigned short* W1T   = (unsigned short*)ws; ws += (size_t)T_ * HID_ * D_ * 2;
    unsigned short* W2T   = (unsigned short*)ws; ws += (size_t)T_ * D_ * HID_ * 2;
    unsigned short* edges = (unsigned short*)ws; ws += (size_t)B_ * E_ * D_ * 2;    // 8 MB
    unsigned short* efT   = (unsigned short*)ws; ws += (size_t)B_ * D_ * E_ * 2;    // 8 MB

    hipLaunchKernelGGL(k_prep_w, dim3(320), dim3(256), 0, stream, W1, W2, W1T, W2T);
    hipLaunchKernelGGL(k_ori_prep, dim3(8, 64), dim3(256), 0, stream, ori, out, oriT);
    hipLaunchKernelGGL(k_gemm_edges, dim3(8, 64), dim3(256), 0, stream, H, oriT, edges);
    hipLaunchKernelGGL(k_mlp, dim3(1024), dim3(256), 0, stream, edges, ed, b1, b2, W1T, W2T, efT);
    hipLaunchKernelGGL(k_gemm_out, dim3(8, 64), dim3(256), 0, stream, H, efT, out);
}

// Round 8
// 276.788 us; speedup vs baseline: 1.2926x; 1.0699x over previous
//
#include <hip/hip_runtime.h>

#define B_   64
#define E_   1024
#define N_   512
#define D_   64
#define HID_ 128
#define T_   5

typedef __bf16 bf16x8 __attribute__((ext_vector_type(8)));
typedef float f32x4 __attribute__((ext_vector_type(4)));

__device__ __forceinline__ unsigned short f2bu(float f) {
    union { float f; unsigned int u; } v; v.f = f;
    unsigned int r = (v.u + 0x7fffu + ((v.u >> 16) & 1u)) >> 16;  // RNE
    return (unsigned short)r;
}

__device__ __forceinline__ unsigned int pack2(float lo, float hi) {
    union { __bf16 b[2]; unsigned int u; } v;
    v.b[0] = (__bf16)lo; v.b[1] = (__bf16)hi;   // RNE
    return v.u;
}

__device__ __forceinline__ uint4 cvt8(float4 a, float4 b) {
    union { __bf16 h[8]; uint4 u; } v;
    v.h[0] = (__bf16)a.x; v.h[1] = (__bf16)a.y; v.h[2] = (__bf16)a.z; v.h[3] = (__bf16)a.w;
    v.h[4] = (__bf16)b.x; v.h[5] = (__bf16)b.y; v.h[6] = (__bf16)b.z; v.h[7] = (__bf16)b.w;
    return v.u;
}

#define MFMA16(a, b, c) __builtin_amdgcn_mfma_f32_16x16x32_bf16((a), (b), (c), 0, 0, 0)

// ---------------------------------------------------------------------------
// Prep: W1[t][d][h] -> W1T[t][h][d] bf16 ; W2[t][h][d] -> W2T[t][d][h] bf16
// ---------------------------------------------------------------------------
__global__ __launch_bounds__(256) void k_prep_w(const float* __restrict__ W1,
                                                const float* __restrict__ W2,
                                                unsigned short* __restrict__ W1T,
                                                unsigned short* __restrict__ W2T) {
    int idx = blockIdx.x * 256 + threadIdx.x;
    if (idx < T_ * HID_ * D_) {
        int t = idx / (HID_ * D_), rem = idx % (HID_ * D_);
        int h = rem / D_, d = rem % D_;
        W1T[idx] = f2bu(W1[(t * D_ + d) * HID_ + h]);
    } else {
        int j = idx - T_ * HID_ * D_;
        int t = j / (D_ * HID_), rem = j % (D_ * HID_);
        int d = rem / HID_, h = rem % HID_;
        W2T[j] = f2bu(W2[(t * HID_ + h) * D_ + d]);
    }
}

// ---------------------------------------------------------------------------
// Prep: ori[b][n][d] -> oriT[b][d][n] bf16, and out[b][n][64+d] = ori (fp32)
// grid (8, 64): x = n-tile of 64, y = b
// ---------------------------------------------------------------------------
__global__ __launch_bounds__(256) void k_ori_prep(const float* __restrict__ ori,
                                                  float* __restrict__ out,
                                                  unsigned short* __restrict__ oriT) {
    int b = blockIdx.y, n0 = blockIdx.x * 64;
    __shared__ float tl[64 * 65];
    int tid = threadIdx.x;
    int dl = tid & 63;
    #pragma unroll 4
    for (int p = 0; p < 16; ++p) {
        int nn = p * 4 + (tid >> 6);
        float v = ori[(size_t)(b * N_ + n0 + nn) * D_ + dl];
        out[(size_t)(b * N_ + n0 + nn) * 128 + 64 + dl] = v;
        tl[dl * 65 + nn] = v;
    }
    __syncthreads();
    #pragma unroll 4
    for (int p = 0; p < 16; ++p) {
        int dd = p * 4 + (tid >> 6);
        oriT[(size_t)(b * D_ + dd) * N_ + n0 + dl] = f2bu(tl[dd * 65 + dl]);
    }
}

// ---------------------------------------------------------------------------
// Fused K1+K2: per block (b, e-tile of 64):
//   Phase 1: edges tile = H[b][e0..e0+64][:] @ ori[b]  (MFMA, BK=64, inline
//            fp32->bf16 cvt of H) -> LDS a_sh (C-layout -> [r][d] roundtrip)
//   Phase 2: per-type MLP + mixture (verbatim k_mlp t-loop) -> efT
// grid 1024: b = bx>>4, e0 = (bx&15)*64. 256 threads = 4 waves.
// ---------------------------------------------------------------------------
__global__ __launch_bounds__(256) void k_edge_mlp(const float* __restrict__ H,
                                                  const unsigned short* __restrict__ oriT,
                                                  const float* __restrict__ ed,
                                                  const float* __restrict__ b1,
                                                  const float* __restrict__ b2,
                                                  const unsigned short* __restrict__ W1T,
                                                  const unsigned short* __restrict__ W2T,
                                                  unsigned short* __restrict__ efT) {
    int bx = blockIdx.x;
    int b = bx >> 4, e0 = (bx & 15) * 64;
    __shared__ __align__(16) unsigned short aA[64 * 72];     // H-tile staging
    __shared__ __align__(16) unsigned short bB[64 * 72];     // oriT staging
    __shared__ __align__(16) unsigned short a_sh[64 * 72];   // edges tile [r][d]
    __shared__ __align__(16) unsigned short w_sh[128 * 72];  // W1T / W2T (aliased)
    __shared__ __align__(16) unsigned short h_sh[64 * 136];  // h' tile [r][hid]
    __shared__ float wd_sh[320];
    __shared__ float b1_sh[640];
    __shared__ float b2_sh[320];
    int tid = threadIdx.x, w = tid >> 6, l = tid & 63, q = l >> 4, c = l & 15;

    // small staging (visible by first barrier below)
    for (int u = tid; u < 320; u += 256) wd_sh[u] = ed[((size_t)b * E_ + e0) * T_ + u];
    for (int u = tid; u < 640; u += 256) b1_sh[u] = b1[u];
    for (int u = tid; u < 320; u += 256) b2_sh[u] = b2[u];

    const f32x4 zero = {0.f, 0.f, 0.f, 0.f};

    // ---- Phase 1: edges tile GEMM (M=64 e-rows, N=64 d, K=512 n, BK=64) ----
    f32x4 acc1[4];
    #pragma unroll
    for (int fn = 0; fn < 4; ++fn) acc1[fn] = zero;

    for (int ks = 0; ks < 8; ++ks) {
        int k0 = ks * 64;
        // stage A: 64 e-rows x 64 floats of H -> bf16 (packed cvt)
        #pragma unroll
        for (int p = 0; p < 2; ++p) {
            int u = p * 256 + tid, r = u >> 3, sg = u & 7;
            const float* s = &H[((size_t)b * E_ + e0 + r) * N_ + k0 + sg * 8];
            float4 f0 = *(const float4*)&s[0];
            float4 f1 = *(const float4*)&s[4];
            *(uint4*)&aA[r * 72 + sg * 8] = cvt8(f0, f1);
        }
        // stage B: oriT rows (bf16, n-contig)
        #pragma unroll
        for (int p = 0; p < 2; ++p) {
            int u = p * 256 + tid, r = u >> 3, sg = u & 7;
            *(uint4*)&bB[r * 72 + sg * 8] =
                *(const uint4*)&oriT[((size_t)b * D_ + r) * N_ + k0 + sg * 8];
        }
        __syncthreads();
        #pragma unroll
        for (int h = 0; h < 2; ++h) {
            bf16x8 a0 = *(const bf16x8*)&aA[(w * 16 + c) * 72 + h * 32 + q * 8];
            #pragma unroll
            for (int fn = 0; fn < 4; ++fn) {
                bf16x8 bb = *(const bf16x8*)&bB[(fn * 16 + c) * 72 + h * 32 + q * 8];
                acc1[fn] = MFMA16(a0, bb, acc1[fn]);
            }
        }
        __syncthreads();
    }
    // C-layout -> a_sh[r][d] (bf16), same quantization point as old edges buf
    #pragma unroll
    for (int fn = 0; fn < 4; ++fn)
        #pragma unroll
        for (int i = 0; i < 4; ++i)
            a_sh[(w * 16 + q * 4 + i) * 72 + fn * 16 + c] = f2bu(acc1[fn][i]);
    // visibility handled by B0 barrier at top of t-loop

    // ---- Phase 2: per-type MLP + mixture (k_mlp body, verified) ----
    f32x4 y[4];
    #pragma unroll
    for (int fn = 0; fn < 4; ++fn) y[fn] = zero;

    for (int t = 0; t < T_; ++t) {
        __syncthreads();  // B0: a_sh/wd/b1/b2 visible; prev GEMM2 done with w_sh/h_sh
        #pragma unroll
        for (int p = 0; p < 4; ++p) {  // W1T[t]: 128 rows x 64 bf16 = 1024 uint4
            int u = p * 256 + tid, hh = u >> 3, sg = u & 7;
            *(uint4*)&w_sh[hh * 72 + sg * 8] =
                *(const uint4*)&W1T[(t * HID_ + hh) * D_ + sg * 8];
        }
        __syncthreads();  // B1
        f32x4 hc[8];
        #pragma unroll
        for (int fn = 0; fn < 8; ++fn) hc[fn] = zero;
        #pragma unroll
        for (int ks = 0; ks < 2; ++ks) {
            bf16x8 a = *(const bf16x8*)&a_sh[(w * 16 + c) * 72 + ks * 32 + q * 8];
            #pragma unroll
            for (int fn = 0; fn < 8; ++fn) {
                bf16x8 bb = *(const bf16x8*)&w_sh[(fn * 16 + c) * 72 + ks * 32 + q * 8];
                hc[fn] = MFMA16(a, bb, hc[fn]);
            }
        }
        float wv[4];
        #pragma unroll
        for (int i = 0; i < 4; ++i) wv[i] = wd_sh[(w * 16 + q * 4 + i) * T_ + t];
        #pragma unroll
        for (int fn = 0; fn < 8; ++fn) {
            float b1v = b1_sh[t * HID_ + fn * 16 + c];
            #pragma unroll
            for (int i = 0; i < 4; ++i) {
                float v = hc[fn][i] + b1v;
                v = fmaxf(v, 0.0f) * wv[i];
                h_sh[(w * 16 + q * 4 + i) * 136 + fn * 16 + c] = f2bu(v);
            }
        }
        __syncthreads();  // B2: GEMM1 w_sh reads + h_sh writes complete
        #pragma unroll
        for (int p = 0; p < 4; ++p) {  // W2T[t]: 64 rows x 128 bf16 = 1024 uint4
            int u = p * 256 + tid, dd = u >> 4, sg = u & 15;
            *(uint4*)&w_sh[dd * 136 + sg * 8] =
                *(const uint4*)&W2T[(t * D_ + dd) * HID_ + sg * 8];
        }
        __syncthreads();  // B3
        #pragma unroll
        for (int ks = 0; ks < 4; ++ks) {
            bf16x8 a = *(const bf16x8*)&h_sh[(w * 16 + c) * 136 + ks * 32 + q * 8];
            #pragma unroll
            for (int fn = 0; fn < 4; ++fn) {
                bf16x8 bb = *(const bf16x8*)&w_sh[(fn * 16 + c) * 136 + ks * 32 + q * 8];
                y[fn] = MFMA16(a, bb, y[fn]);
            }
        }
    }
    // epilogue: + sum_t w*b2, write efT[b][d][e] transposed (bf16 ushort4)
    #pragma unroll
    for (int fn = 0; fn < 4; ++fn) {
        int d = fn * 16 + c;
        ushort4 o;
        #pragma unroll
        for (int i = 0; i < 4; ++i) {
            int r = w * 16 + q * 4 + i;
            float s = y[fn][i];
            #pragma unroll
            for (int t = 0; t < T_; ++t) s += wd_sh[r * T_ + t] * b2_sh[t * D_ + d];
            ((unsigned short*)&o)[i] = f2bu(s);
        }
        *(ushort4*)&efT[((size_t)b * D_ + d) * E_ + e0 + w * 16 + q * 4] = o;
    }
}

// ---------------------------------------------------------------------------
// K3: out[b][n][d] = sum_e H[b][e][n] * ef[b][e][d], computed as outT tile
// (M = d 64, N = n-tile 64, K = e 1024, BK = 64). Unchanged (verified R7).
// ---------------------------------------------------------------------------
__global__ __launch_bounds__(256) void k_gemm_out(const float* __restrict__ H,
                                                  const unsigned short* __restrict__ efT,
                                                  float* __restrict__ out) {
    int b = blockIdx.y, n0 = blockIdx.x * 64;
    __shared__ __align__(16) unsigned short aA[64 * 72];   // efT [d][e]
    __shared__ unsigned int bB32[64 * 33];                 // H^T [n][e/2] pair-packed
    int tid = threadIdx.x, w = tid >> 6, l = tid & 63, q = l >> 4, c = l & 15;
    int r2 = tid >> 3, cg = tid & 7;
    const f32x4 zero = {0.f, 0.f, 0.f, 0.f};
    f32x4 acc[4];
    #pragma unroll
    for (int fm = 0; fm < 4; ++fm) acc[fm] = zero;

    for (int ks = 0; ks < 16; ++ks) {
        int k0 = ks * 64;
        #pragma unroll
        for (int p = 0; p < 2; ++p) {
            int u = p * 256 + tid, r = u >> 3, sg = u & 7;
            *(uint4*)&aA[r * 72 + sg * 8] =
                *(const uint4*)&efT[((size_t)b * D_ + r) * E_ + k0 + sg * 8];
        }
        {
            const float* s0 = &H[((size_t)b * E_ + k0 + 2 * r2) * N_ + n0 + cg * 8];
            const float* s1 = s0 + N_;
            float4 f0 = *(const float4*)&s0[0], f1 = *(const float4*)&s0[4];
            float4 g0 = *(const float4*)&s1[0], g1 = *(const float4*)&s1[4];
            float r0[8] = {f0.x, f0.y, f0.z, f0.w, f1.x, f1.y, f1.z, f1.w};
            float r1[8] = {g0.x, g0.y, g0.z, g0.w, g1.x, g1.y, g1.z, g1.w};
            #pragma unroll
            for (int j = 0; j < 8; ++j)
                bB32[(cg * 8 + j) * 33 + r2] = pack2(r0[j], r1[j]);
        }
        __syncthreads();
        #pragma unroll
        for (int h = 0; h < 2; ++h) {
            union { unsigned int u[4]; bf16x8 v; } bb;
            #pragma unroll
            for (int i = 0; i < 4; ++i)
                bb.u[i] = bB32[(w * 16 + c) * 33 + h * 16 + q * 4 + i];
            #pragma unroll
            for (int fm = 0; fm < 4; ++fm) {
                bf16x8 afr = *(const bf16x8*)&aA[(fm * 16 + c) * 72 + h * 32 + q * 8];
                acc[fm] = MFMA16(afr, bb.v, acc[fm]);
            }
        }
        __syncthreads();
    }
    #pragma unroll
    for (int fm = 0; fm < 4; ++fm) {
        *(f32x4*)&out[((size_t)b * N_ + n0 + w * 16 + c) * 128 + fm * 16 + q * 4] = acc[fm];
    }
}

// ---------------------------------------------------------------------------
extern "C" void kernel_launch(void* const* d_in, const int* in_sizes, int n_in,
                              void* d_out, int out_size, void* d_ws, size_t ws_size,
                              hipStream_t stream) {
    const float* ed  = (const float*)d_in[0];  // [B,E,T]
    const float* H   = (const float*)d_in[1];  // [B,E,N]
    const float* ori = (const float*)d_in[2];  // [B,N,64]
    const float* W1  = (const float*)d_in[3];  // [T,64,128]
    const float* b1  = (const float*)d_in[4];  // [T,128]
    const float* W2  = (const float*)d_in[5];  // [T,128,64]
    const float* b2  = (const float*)d_in[6];  // [T,64]
    float* out = (float*)d_out;

    char* ws = (char*)d_ws;
    unsigned short* oriT = (unsigned short*)ws; ws += (size_t)B_ * D_ * N_ * 2;    // 4 MB
    unsigned short* W1T  = (unsigned short*)ws; ws += (size_t)T_ * HID_ * D_ * 2;
    unsigned short* W2T  = (unsigned short*)ws; ws += (size_t)T_ * D_ * HID_ * 2;
    unsigned short* efT  = (unsigned short*)ws; ws += (size_t)B_ * D_ * E_ * 2;    // 8 MB

    hipLaunchKernelGGL(k_prep_w, dim3(320), dim3(256), 0, stream, W1, W2, W1T, W2T);
    hipLaunchKernelGGL(k_ori_prep, dim3(8, 64), dim3(256), 0, stream, ori, out, oriT);
    hipLaunchKernelGGL(k_edge_mlp, dim3(1024), dim3(256), 0, stream,
                       H, oriT, ed, b1, b2, W1T, W2T, efT);
    hipLaunchKernelGGL(k_gemm_out, dim3(8, 64), dim3(256), 0, stream, H, efT, out);
}